// Round 2
// baseline (3586.691 us; speedup 1.0000x reference)
//
#include <hip/hip_runtime.h>
#include <math.h>

// Problem constants
#define B_      32
#define S_      512
#define H_      256
#define EMB_    256
#define M_      (B_*S_)     // 16384
#define N7_     1792        // 7*H
#define NG_     2048        // reordered gate width: 8 cols per hidden unit t
#define NS_     2560        // smalls: 2048 reordered (gV | gw) + 512 fo
#define KA_     1024        // augmented K: 3H (shifted h) + EMB (emb)
#define LABEL_  16

__device__ __forceinline__ float sigf(float x){ return 1.f/(1.f+__expf(-x)); }

// ---------------------------------------------------------------------------
// Waug[1024][2048], column j = t*8+p  (t = hidden unit, p = gate):
//   p<7 : rows 0:768 = Ws[k][p*256+t], rows 768:1024 = Us[k-768][p*256+t]
//   p==7: rows 256:512 = ugu[k-256][t]  (center-h -> f_w logits), else 0
__global__ void prep_waug(const float* __restrict__ Ws, const float* __restrict__ Us,
                          const float* __restrict__ ugu, float* __restrict__ Waug){
    int idx = blockIdx.x*256 + threadIdx.x;      // over 1024*2048
    int k = idx >> 11, j = idx & (NG_-1);
    int t = j >> 3, p = j & 7;
    float v = 0.f;
    if(p < 7){
        int col = p*256 + t;
        v = (k < 768) ? Ws[k*N7_ + col] : Us[(k-768)*N7_ + col];
    } else if(k >= 256 && k < 512){
        v = ugu[(k-256)*H_ + t];
    }
    Waug[idx] = v;
}

// ---------------------------------------------------------------------------
// h0 = c0 = (E[node_text] @ Wp + bp) * mask      (M=16384, K=256, N=256)
__global__ void embed_gemm(const int* __restrict__ idx, const float* __restrict__ E,
                           const float* __restrict__ Wp, const float* __restrict__ bp,
                           const float* __restrict__ mask,
                           float* __restrict__ h0, float* __restrict__ c0){
    __shared__ float As[16][65];
    __shared__ float Bs[16][64];
    __shared__ int   rid[64];
    int tid = threadIdx.x;
    int n0 = blockIdx.x*64, m0 = blockIdx.y*64;
    if(tid < 64) rid[tid] = idx[m0 + tid];
    __syncthreads();
    int tm = tid>>4, tn = tid&15;
    int la_r = tid>>4, la_k = tid&15;
    int lb_k = tid>>6, lb_j = tid&63;
    float acc[4][4] = {};
    for(int kt=0; kt<EMB_; kt+=16){
        #pragma unroll
        for(int q=0;q<4;q++){
            int r = la_r + q*16;
            As[la_k][r] = E[(long)rid[r]*EMB_ + kt + la_k];
        }
        #pragma unroll
        for(int q=0;q<4;q++){
            int k = kt + lb_k + q*4;
            Bs[lb_k+q*4][lb_j] = Wp[k*H_ + n0 + lb_j];
        }
        __syncthreads();
        #pragma unroll
        for(int kk=0;kk<16;kk++){
            float a[4], b[4];
            #pragma unroll
            for(int x=0;x<4;x++){ a[x]=As[kk][tm*4+x]; b[x]=Bs[kk][tn*4+x]; }
            #pragma unroll
            for(int x=0;x<4;x++)
                #pragma unroll
                for(int y=0;y<4;y++) acc[x][y] += a[x]*b[y];
        }
        __syncthreads();
    }
    #pragma unroll
    for(int x=0;x<4;x++){
        int i = m0 + tm*4 + x;
        float m = mask[i];
        #pragma unroll
        for(int y=0;y<4;y++){
            int j = n0 + tn*4 + y;
            float v = (acc[x][y] + bp[j]) * m;
            h0[(long)i*H_ + j] = v;
            c0[(long)i*H_ + j] = v;
        }
    }
}

// ---------------------------------------------------------------------------
// mean over S:  out[b,h] = (1/S) * sum_s h[b,s,h]; optionally duplicate to outB
__global__ void reduce_mean_s(const float* __restrict__ h, float* __restrict__ outA,
                              float* __restrict__ outB){
    __shared__ float part[4][256];
    int b = blockIdx.x;
    int hh = threadIdx.x & 255, sg = threadIdx.x >> 8;
    float s = 0.f;
    long base = ((long)b*S_ + sg*128)*H_ + hh;
    for(int ss=0; ss<128; ss++) s += h[base + (long)ss*H_];
    part[sg][hh] = s;
    __syncthreads();
    if(threadIdx.x < 256){
        float t = (part[0][hh]+part[1][hh]+part[2][hh]+part[3][hh]) * (1.f/S_);
        outA[b*H_+hh] = t;
        if(outB) outB[b*H_+hh] = t;
    }
}

// ---------------------------------------------------------------------------
// smalls[32][2560]:
//   cols 0:2048 (reordered j=t*8+p): p<7 -> bVs[p*256+t] + g@Vs[:,p*256+t]
//                                    p==7 -> bgu[t] + g@Wgw[:,t]
//   cols 2048:2560 = sigmoid(g @ WgW + h_avg @ UgU + bgU)   (f_g | o_g)
__global__ void small_gemm(const float* __restrict__ g, const float* __restrict__ havg,
                           const float* __restrict__ Vs, const float* __restrict__ bVs,
                           const float* __restrict__ Wgw, const float* __restrict__ bgu,
                           const float* __restrict__ WgW, const float* __restrict__ UgU,
                           const float* __restrict__ bgU, float* __restrict__ smalls){
    __shared__ float gs[256], hs[256];
    int b = blockIdx.y, t0 = threadIdx.x;
    gs[t0] = g[b*H_+t0];
    hs[t0] = havg[b*H_+t0];
    __syncthreads();
    int j = blockIdx.x*256 + t0;
    float acc;
    if(j < NG_){
        int t = j >> 3, p = j & 7;
        if(p < 7){
            int col = p*256 + t;
            acc = bVs[col];
            for(int k=0;k<H_;k++) acc += gs[k]*Vs[k*N7_+col];
        } else {
            acc = bgu[t];
            for(int k=0;k<H_;k++) acc += gs[k]*Wgw[k*H_+t];
        }
    } else {
        int jj = j - NG_;
        acc = bgU[jj];
        for(int k=0;k<H_;k++) acc += gs[k]*WgW[k*512+jj] + hs[k]*UgU[k*512+jj];
        acc = sigf(acc);
    }
    smalls[b*NS_+j] = acc;
}

// ---------------------------------------------------------------------------
// Fused gates-GEMM + SCell.  A[i,k]: k<768 -> shifted h (dlt = k/256 - 1),
// k>=768 -> E[node_text[i], k-768].  B = Waug (reordered).  Epilogue adds
// smalls, exchanges through LDS so each thread owns complete 8-gate groups,
// applies SCell, writes h_new/c_new and the f_w logits (hu) for GCell.
__global__ void layer_fused(const int* __restrict__ idx, const float* __restrict__ E,
                            const float* __restrict__ h_old, const float* __restrict__ c_old,
                            const float* __restrict__ cg_old, const float* __restrict__ Waug,
                            const float* __restrict__ smalls, const float* __restrict__ mask,
                            float* __restrict__ h_new, float* __restrict__ c_new,
                            float* __restrict__ hu_out){
    __shared__ float As[16][65];
    __shared__ float Bs[16][64];
    __shared__ float Gs[64][65];
    __shared__ int   rid[64];
    int tid = threadIdx.x;
    int n0 = blockIdx.x*64, m0 = blockIdx.y*64;
    int b = m0 >> 9;                       // 64-row tile lies in one batch b
    if(tid < 64) rid[tid] = idx[m0 + tid];
    __syncthreads();
    int tm = tid>>4, tn = tid&15;
    int la_r = tid>>4, la_k = tid&15;
    int lb_k = tid>>6, lb_j = tid&63;
    float acc[4][4] = {};
    for(int kt=0; kt<KA_; kt+=16){
        if(kt < 768){
            int dlt = (kt>>8) - 1;         // -1, 0, +1
            int kk0 = (kt & 255) + la_k;
            #pragma unroll
            for(int q=0;q<4;q++){
                int r = la_r + q*16;
                int i = m0 + r;
                int si = (i & (S_-1)) + dlt;
                float v = 0.f;
                if(si >= 0 && si < S_) v = h_old[(long)(i+dlt)*H_ + kk0];
                As[la_k][r] = v;
            }
        } else {
            int ke = kt - 768 + la_k;
            #pragma unroll
            for(int q=0;q<4;q++){
                int r = la_r + q*16;
                As[la_k][r] = E[(long)rid[r]*EMB_ + ke];
            }
        }
        #pragma unroll
        for(int q=0;q<4;q++){
            int k = kt + lb_k + q*4;
            Bs[lb_k+q*4][lb_j] = Waug[(long)k*NG_ + n0 + lb_j];
        }
        __syncthreads();
        #pragma unroll
        for(int kk=0;kk<16;kk++){
            float a[4], bb[4];
            #pragma unroll
            for(int x=0;x<4;x++){ a[x]=As[kk][tm*4+x]; bb[x]=Bs[kk][tn*4+x]; }
            #pragma unroll
            for(int x=0;x<4;x++)
                #pragma unroll
                for(int y=0;y<4;y++) acc[x][y] += a[x]*bb[y];
        }
        __syncthreads();
    }
    // stage gates (+ per-batch smalls) into LDS for the 8-gate exchange
    #pragma unroll
    for(int x=0;x<4;x++)
        #pragma unroll
        for(int y=0;y<4;y++){
            int j = n0 + tn*4 + y;
            Gs[tm*4+x][tn*4+y] = acc[x][y] + smalls[b*NS_ + j];
        }
    __syncthreads();
    // SCell: 512 (row, t) pairs per block, 2 per thread
    #pragma unroll
    for(int qq=0; qq<2; qq++){
        int q = tid + 256*qq;
        int r = q >> 3, tgl = q & 7;
        int i = m0 + r;
        int t = (n0 >> 3) + tgl;
        float gv[8];
        #pragma unroll
        for(int p=0;p<8;p++) gv[p] = Gs[r][tgl*8+p];
        float ei=__expf(sigf(gv[0])), el=__expf(sigf(gv[1])), er=__expf(sigf(gv[2]));
        float ef=__expf(sigf(gv[3])), es=__expf(sigf(gv[4]));
        float inv = 1.f/(ei+el+er+ef+es);
        int s = i & (S_-1);
        float c0v = c_old[(long)i*H_+t];
        float cb = (s>0)     ? c_old[(long)(i-1)*H_+t] : 0.f;
        float ca = (s<S_-1)  ? c_old[(long)(i+1)*H_+t] : 0.f;
        float cg = cg_old[b*H_+t];
        float tu = tanhf(gv[6]);
        float nc = (cb*el + c0v*ef + er*ca + es*cg + ei*tu)*inv;
        float nh = gv[5] * tanhf(nc);      // o gate stays raw (as in source)
        float m = mask[i];
        c_new[(long)i*H_+t]  = nc*m;
        h_new[(long)i*H_+t]  = nh*m;
        hu_out[(long)i*H_+t] = gv[7];
    }
}

// ---------------------------------------------------------------------------
// GCell: softmax over S of sigmoid(hu)-neg, weighted sum with old c.
__global__ void gcell(const float* __restrict__ hu, const float* __restrict__ c_old,
                      const float* __restrict__ cg_old, const float* __restrict__ smalls,
                      const float* __restrict__ mask,
                      float* __restrict__ g_new, float* __restrict__ cg_new){
    int b = blockIdx.x, t = threadIdx.x;
    float l = 0.f, acc = 0.f;
    for(int s=0; s<S_; s++){
        long i = (long)b*S_ + s;
        float x = sigf(hu[i*H_+t]) - (1.f - mask[i])*1e16f;
        float e = __expf(x);
        l += e;
        acc += e * c_old[i*H_+t];
    }
    float fg = smalls[b*NS_ + NG_ + t];
    float og = smalls[b*NS_ + NG_ + 256 + t];
    float ncg = fg*cg_old[b*H_+t] + acc/l;
    g_new[b*H_+t]  = og*tanhf(ncg);
    cg_new[b*H_+t] = ncg;
}

// ---------------------------------------------------------------------------
// out[0:512] = g@Wo + bo ; out[512:528] = mean over b of the first part
__global__ void outk(const float* __restrict__ g, const float* __restrict__ Wo,
                     const float* __restrict__ bo, float* __restrict__ out){
    __shared__ float o1[B_*LABEL_];
    int t = threadIdx.x;
    if(t < B_*LABEL_){
        int b = t/LABEL_, j = t%LABEL_;
        float acc = bo[j];
        for(int k=0;k<H_;k++) acc += g[b*H_+k]*Wo[k*LABEL_+j];
        o1[t] = acc;
        out[t] = acc;
    }
    __syncthreads();
    if(t < LABEL_){
        float s = 0.f;
        for(int b=0;b<B_;b++) s += o1[b*LABEL_+t];
        out[B_*LABEL_+t] = s*(1.f/B_);
    }
}

// ---------------------------------------------------------------------------
extern "C" void kernel_launch(void* const* d_in, const int* in_sizes, int n_in,
                              void* d_out, int out_size, void* d_ws, size_t ws_size,
                              hipStream_t stream){
    const int*   node_text = (const int*)  d_in[2];
    const float* word_mask = (const float*)d_in[3];
    const float* E   = (const float*)d_in[7];
    const float* Wp  = (const float*)d_in[8];
    const float* bp  = (const float*)d_in[9];
    const float* Ws  = (const float*)d_in[10];
    const float* Us  = (const float*)d_in[11];
    const float* Vs  = (const float*)d_in[12];
    const float* bVs = (const float*)d_in[13];
    const float* WgW = (const float*)d_in[14];
    const float* Wgw = (const float*)d_in[15];
    const float* UgU = (const float*)d_in[16];
    const float* bgU = (const float*)d_in[17];
    const float* ugu = (const float*)d_in[18];
    const float* bgu = (const float*)d_in[19];
    const float* Wo  = (const float*)d_in[20];
    const float* bo  = (const float*)d_in[21];

    float* w = (float*)d_ws;
    size_t off = 0;
    auto alloc = [&](size_t n){ float* p = w + off; off += n; return p; };
    float* Waug   = alloc((size_t)KA_*NG_);      //  8.4 MB
    float* hb[2]  = { alloc((size_t)M_*H_), alloc((size_t)M_*H_) };   // 33.6 MB
    float* cb[2]  = { alloc((size_t)M_*H_), alloc((size_t)M_*H_) };   // 33.6 MB
    float* hu     = alloc((size_t)M_*H_);        // 16.8 MB
    float* gb[2]  = { alloc(B_*H_), alloc(B_*H_) };
    float* cgb[2] = { alloc(B_*H_), alloc(B_*H_) };
    float* havg   = alloc(B_*H_);
    float* smalls = alloc((size_t)B_*NS_);
    // total ~ 93 MB in d_ws

    prep_waug<<<(KA_*NG_)/256, 256, 0, stream>>>(Ws, Us, ugu, Waug);
    embed_gemm<<<dim3(H_/64, M_/64), 256, 0, stream>>>(node_text, E, Wp, bp,
                                                       word_mask, hb[0], cb[0]);
    reduce_mean_s<<<B_, 1024, 0, stream>>>(hb[0], gb[0], cgb[0]);

    int cur = 0;
    for(int layer=0; layer<3; layer++){
        int nxt = cur ^ 1;
        reduce_mean_s<<<B_, 1024, 0, stream>>>(hb[cur], havg, nullptr);
        small_gemm<<<dim3(NS_/256, B_), 256, 0, stream>>>(gb[cur], havg, Vs, bVs,
                                                          Wgw, bgu, WgW, UgU, bgU, smalls);
        layer_fused<<<dim3(NG_/64, M_/64), 256, 0, stream>>>(node_text, E, hb[cur], cb[cur],
                                                             cgb[cur], Waug, smalls, word_mask,
                                                             hb[nxt], cb[nxt], hu);
        gcell<<<B_, 256, 0, stream>>>(hu, cb[cur], cgb[cur], smalls, word_mask,
                                      gb[nxt], cgb[nxt]);
        cur = nxt;
    }
    outk<<<1, 512, 0, stream>>>(gb[cur], Wo, bo, (float*)d_out);
}

// Round 3
// 473.325 us; speedup vs baseline: 7.5777x; 7.5777x over previous
//
#include <hip/hip_runtime.h>
#include <math.h>

// Problem constants
#define B_      32
#define S_      512
#define H_      256
#define EMB_    256
#define M_      (B_*S_)     // 16384
#define N7_     1792        // 7*H
#define NG_     2048        // reordered gate width
#define NS_     2560        // smalls: 2048 reordered + 512 fo
#define KA_     1024        // augmented K: 3H (shifted h) + EMB (emb)
#define LABEL_  16

// GEMM tile
#define BM 128
#define BN 256
#define BK 32

typedef __bf16 bf16x8 __attribute__((ext_vector_type(8)));
typedef float  f32x4  __attribute__((ext_vector_type(4)));

__device__ __forceinline__ float sigf(float x){ return 1.f/(1.f+__expf(-x)); }

__device__ __forceinline__ unsigned short f2bf(float f){
    union { float f; unsigned int u; } v; v.f = f;
    unsigned int r = v.u + 0x7FFFu + ((v.u >> 16) & 1u);   // RNE
    return (unsigned short)(r >> 16);
}
__device__ __forceinline__ float bf2f(unsigned short u){
    union { unsigned int i; float f; } v; v.i = ((unsigned int)u) << 16; return v.f;
}

// ---------------------------------------------------------------------------
// WaugT[j=0..2047][k=0..1023] bf16, column order j = (t>>4)*128 + p*16 + (t&15):
//   p<7 : k<768 -> Ws[k][p*256+t] ; k>=768 -> Us[k-768][p*256+t]
//   p==7: k in [256,512) -> ugu[k-256][t], else 0    (f_w logits)
// Also zeroes the 256-entry zero page (OOB staging target).
__global__ void prep_waugT(const float* __restrict__ Ws, const float* __restrict__ Us,
                           const float* __restrict__ ugu, unsigned short* __restrict__ WaugT,
                           unsigned short* __restrict__ zpage){
    if(blockIdx.x == 0) zpage[threadIdx.x] = 0;
    long idx = (long)blockIdx.x*256 + threadIdx.x;       // over 2048*1024
    int j = (int)(idx >> 10), k = (int)(idx & 1023);
    int tg = j >> 7, rem = j & 127, p = rem >> 4, t = tg*16 + (rem & 15);
    float v = 0.f;
    if(p < 7){
        int col = p*256 + t;
        v = (k < 768) ? Ws[(long)k*N7_ + col] : Us[(long)(k-768)*N7_ + col];
    } else if(k >= 256 && k < 512){
        v = ugu[(k-256)*H_ + t];
    }
    WaugT[idx] = f2bf(v);
}

// ---------------------------------------------------------------------------
// embbf[i][k] = bf16(E[node_text[i]][k])
__global__ void emb_cast(const int* __restrict__ idx, const float* __restrict__ E,
                         unsigned short* __restrict__ embbf){
    int i = blockIdx.x, t = threadIdx.x;
    embbf[(size_t)i*EMB_ + t] = f2bf(E[(size_t)idx[i]*EMB_ + t]);
}

// ---------------------------------------------------------------------------
// h0(bf16) = c0(f32) = (E[node_text] @ Wp + bp) * mask    (fp32 GEMM, small)
__global__ void embed_gemm(const int* __restrict__ idx, const float* __restrict__ E,
                           const float* __restrict__ Wp, const float* __restrict__ bp,
                           const float* __restrict__ mask,
                           unsigned short* __restrict__ h0b, float* __restrict__ c0){
    __shared__ float As[16][65];
    __shared__ float Bs[16][64];
    __shared__ int   rid[64];
    int tid = threadIdx.x;
    int n0 = blockIdx.x*64, m0 = blockIdx.y*64;
    if(tid < 64) rid[tid] = idx[m0 + tid];
    __syncthreads();
    int tm = tid>>4, tn = tid&15;
    int la_r = tid>>4, la_k = tid&15;
    int lb_k = tid>>6, lb_j = tid&63;
    float acc[4][4] = {};
    for(int kt=0; kt<EMB_; kt+=16){
        #pragma unroll
        for(int q=0;q<4;q++){
            int r = la_r + q*16;
            As[la_k][r] = E[(long)rid[r]*EMB_ + kt + la_k];
        }
        #pragma unroll
        for(int q=0;q<4;q++){
            int k = kt + lb_k + q*4;
            Bs[lb_k+q*4][lb_j] = Wp[k*H_ + n0 + lb_j];
        }
        __syncthreads();
        #pragma unroll
        for(int kk=0;kk<16;kk++){
            float a[4], b[4];
            #pragma unroll
            for(int x=0;x<4;x++){ a[x]=As[kk][tm*4+x]; b[x]=Bs[kk][tn*4+x]; }
            #pragma unroll
            for(int x=0;x<4;x++)
                #pragma unroll
                for(int y=0;y<4;y++) acc[x][y] += a[x]*b[y];
        }
        __syncthreads();
    }
    #pragma unroll
    for(int x=0;x<4;x++){
        int i = m0 + tm*4 + x;
        float m = mask[i];
        #pragma unroll
        for(int y=0;y<4;y++){
            int j = n0 + tn*4 + y;
            float v = (acc[x][y] + bp[j]) * m;
            h0b[(size_t)i*H_ + j] = f2bf(v);
            c0 [(size_t)i*H_ + j] = v;
        }
    }
}

// ---------------------------------------------------------------------------
// mean over S of bf16 h: out[b,h]; optionally duplicate to outB
__global__ void reduce_mean_s(const unsigned short* __restrict__ h, float* __restrict__ outA,
                              float* __restrict__ outB){
    __shared__ float part[4][256];
    int b = blockIdx.x;
    int hh = threadIdx.x & 255, sg = threadIdx.x >> 8;
    float s = 0.f;
    long base = ((long)b*S_ + sg*128)*H_ + hh;
    for(int ss=0; ss<128; ss++) s += bf2f(h[base + (long)ss*H_]);
    part[sg][hh] = s;
    __syncthreads();
    if(threadIdx.x < 256){
        float t = (part[0][hh]+part[1][hh]+part[2][hh]+part[3][hh]) * (1.f/S_);
        outA[b*H_+hh] = t;
        if(outB) outB[b*H_+hh] = t;
    }
}

// ---------------------------------------------------------------------------
// smalls[32][2560]: cols 0:2048 reordered j=(t>>4)*128+p*16+(t&15):
//   p<7 -> bVs[p*256+t] + g@Vs[:,p*256+t] ;  p==7 -> bgu[t] + g@Wgw[:,t]
// cols 2048:2560 = sigmoid(g@WgW + h_avg@UgU + bgU)  (f_g | o_g)
__global__ void small_gemm(const float* __restrict__ g, const float* __restrict__ havg,
                           const float* __restrict__ Vs, const float* __restrict__ bVs,
                           const float* __restrict__ Wgw, const float* __restrict__ bgu,
                           const float* __restrict__ WgW, const float* __restrict__ UgU,
                           const float* __restrict__ bgU, float* __restrict__ smalls){
    __shared__ float gs[256], hs[256];
    int b = blockIdx.y, t0 = threadIdx.x;
    gs[t0] = g[b*H_+t0];
    hs[t0] = havg[b*H_+t0];
    __syncthreads();
    int j = blockIdx.x*256 + t0;
    float acc;
    if(j < NG_){
        int tg = j >> 7, rem = j & 127, p = rem >> 4, t = tg*16 + (rem & 15);
        if(p < 7){
            int col = p*256 + t;
            acc = bVs[col];
            for(int k=0;k<H_;k++) acc += gs[k]*Vs[k*N7_+col];
        } else {
            acc = bgu[t];
            for(int k=0;k<H_;k++) acc += gs[k]*Wgw[k*H_+t];
        }
    } else {
        int jj = j - NG_;
        acc = bgU[jj];
        for(int k=0;k<H_;k++) acc += gs[k]*WgW[k*512+jj] + hs[k]*UgU[k*512+jj];
        acc = sigf(acc);
    }
    smalls[b*NS_+j] = acc;
}

// ---------------------------------------------------------------------------
// MFMA gates-GEMM (M=16384, N=2048, K=1024) fused with SCell epilogue.
// A[i,k]: k<768 -> shifted h (dlt=k/256-1, zero-page at seq edges);
//         k>=768 -> embbf[i][k-768].  B = WaugT (pre-transposed, reordered).
// LDS slots XOR-swizzled: phys_slot = logical_kseg ^ ((row>>1)&3); staging
// source uses logical kseg so gl_lds's linear dest lands swizzled (rule #21).
__global__ __launch_bounds__(256, 2) void layer_mfma(
        const unsigned short* __restrict__ hbf, const unsigned short* __restrict__ embbf,
        const unsigned short* __restrict__ WaugT, const unsigned short* __restrict__ zpage,
        const float* __restrict__ c_old, const float* __restrict__ cg_old,
        const float* __restrict__ smalls, const float* __restrict__ mask,
        unsigned short* __restrict__ hbf_new, float* __restrict__ c_new,
        float* __restrict__ hu_out){
    __shared__ unsigned short As[BM*BK];   //  8 KB
    __shared__ unsigned short Bs[BN*BK];   // 16 KB
    int tid = threadIdx.x;
    int w = tid >> 6;
    int l = tid & 63;
    int fr = l & 15, fq = l >> 4;
    int wr = w >> 1, wc = w & 1;
    int n0 = blockIdx.x * BN;
    int m0 = blockIdx.y * BM;
    int b  = m0 >> 9;

    f32x4 acc[4][8];
    #pragma unroll
    for(int m=0;m<4;m++)
        #pragma unroll
        for(int n=0;n<8;n++) acc[m][n] = (f32x4){0.f,0.f,0.f,0.f};

    for(int kt=0; kt<KA_; kt+=BK){
        int region = kt >> 8;
        // ---- stage A (8 KB): 2 gl_lds per thread
        #pragma unroll
        for(int q=0;q<2;q++){
            int u   = q*256 + tid;
            int row = u >> 2;
            int k0  = (((u & 3) ^ ((row >> 1) & 3))) * 8;   // logical kseg
            const unsigned short* src;
            if(region < 3){
                int i  = m0 + row;
                int si = (i & (S_-1)) + region - 1;
                src = ((unsigned)si < (unsigned)S_)
                    ? hbf + (size_t)(i + region - 1)*H_ + (kt & 255) + k0
                    : zpage + k0;
            } else {
                src = embbf + (size_t)(m0 + row)*EMB_ + (kt - 768) + k0;
            }
            __builtin_amdgcn_global_load_lds(
                (const __attribute__((address_space(1))) unsigned int*)src,
                (__attribute__((address_space(3))) unsigned int*)(As + (q*256 + w*64)*8),
                16, 0, 0);
        }
        // ---- stage B (16 KB): 4 gl_lds per thread
        #pragma unroll
        for(int q=0;q<4;q++){
            int v   = q*256 + tid;
            int col = v >> 2;
            int k0  = (((v & 3) ^ ((col >> 1) & 3))) * 8;
            const unsigned short* src = WaugT + (size_t)(n0 + col)*KA_ + kt + k0;
            __builtin_amdgcn_global_load_lds(
                (const __attribute__((address_space(1))) unsigned int*)src,
                (__attribute__((address_space(3))) unsigned int*)(Bs + (q*256 + w*64)*8),
                16, 0, 0);
        }
        __syncthreads();
        // ---- fragments + MFMA
        bf16x8 bf[8];
        #pragma unroll
        for(int n=0;n<8;n++){
            int colr = wc*128 + n*16 + fr;
            int slot = fq ^ ((colr >> 1) & 3);
            bf[n] = *(const bf16x8*)(Bs + colr*BK + slot*8);
        }
        #pragma unroll
        for(int m=0;m<4;m++){
            int rowr = wr*64 + m*16 + fr;
            int slot = fq ^ ((rowr >> 1) & 3);
            bf16x8 af = *(const bf16x8*)(As + rowr*BK + slot*8);
            #pragma unroll
            for(int n=0;n<8;n++)
                acc[m][n] = __builtin_amdgcn_mfma_f32_16x16x32_bf16(af, bf[n], acc[m][n], 0, 0, 0);
        }
        __syncthreads();
    }

    // ---- fused SCell epilogue, fully in-register.
    // Lane owns unit t = blockIdx.x*32 + wc*16 + fr for rows wr*64+m*16+fq*4+j.
    int t = (n0 >> 3) + wc*16 + fr;
    float sm[8];
    #pragma unroll
    for(int n=0;n<8;n++) sm[n] = smalls[b*NS_ + n0 + wc*128 + n*16 + fr];
    float cgv = cg_old[b*H_ + t];
    #pragma unroll
    for(int m=0;m<4;m++){
        #pragma unroll
        for(int j=0;j<4;j++){
            int i = m0 + wr*64 + m*16 + fq*4 + j;
            int s = i & (S_-1);
            float gv[8];
            #pragma unroll
            for(int n=0;n<8;n++) gv[n] = acc[m][n][j] + sm[n];
            float ei=__expf(sigf(gv[0])), el=__expf(sigf(gv[1])), er=__expf(sigf(gv[2]));
            float ef=__expf(sigf(gv[3])), es=__expf(sigf(gv[4]));
            float inv = 1.f/(ei+el+er+ef+es);
            float c0v = c_old[(size_t)i*H_ + t];
            float cbv = (s>0)      ? c_old[(size_t)(i-1)*H_ + t] : 0.f;
            float cav = (s<S_-1)   ? c_old[(size_t)(i+1)*H_ + t] : 0.f;
            float tu = tanhf(gv[6]);
            float nc = (cbv*el + c0v*ef + er*cav + es*cgv + ei*tu)*inv;
            float nh = gv[5]*tanhf(nc);
            float mk = mask[i];
            c_new [(size_t)i*H_ + t] = nc*mk;
            hbf_new[(size_t)i*H_ + t] = f2bf(nh*mk);
            hu_out[(size_t)i*H_ + t] = gv[7];
        }
    }
}

// ---------------------------------------------------------------------------
// GCell stage 1: per (b, 64-s chunk) partial softmax sums (fixed order).
__global__ void gcell1(const float* __restrict__ hu, const float* __restrict__ c_old,
                       const float* __restrict__ mask, float* __restrict__ part){
    int bc = blockIdx.x, b = bc >> 3, ch = bc & 7, t = threadIdx.x;
    float l = 0.f, a = 0.f;
    for(int s2=0; s2<64; s2++){
        long i = (long)b*S_ + ch*64 + s2;
        float x = sigf(hu[i*H_+t]) - (1.f - mask[i])*1e16f;
        float e = __expf(x);
        l += e;
        a += e * c_old[i*H_+t];
    }
    part[((long)bc*2+0)*H_+t] = l;
    part[((long)bc*2+1)*H_+t] = a;
}

// GCell stage 2: combine chunks, apply f_g/o_g.
__global__ void gcell2(const float* __restrict__ part, const float* __restrict__ cg_old,
                       const float* __restrict__ smalls,
                       float* __restrict__ g_new, float* __restrict__ cg_new){
    int b = blockIdx.x, t = threadIdx.x;
    float l = 0.f, a = 0.f;
    for(int ch=0; ch<8; ch++){
        l += part[((long)(b*8+ch)*2+0)*H_+t];
        a += part[((long)(b*8+ch)*2+1)*H_+t];
    }
    float fg = smalls[b*NS_ + NG_ + t];
    float og = smalls[b*NS_ + NG_ + 256 + t];
    float ncg = fg*cg_old[b*H_+t] + a/l;
    g_new[b*H_+t]  = og*tanhf(ncg);
    cg_new[b*H_+t] = ncg;
}

// ---------------------------------------------------------------------------
// out[0:512] = g@Wo + bo ; out[512:528] = mean over b of the first part
__global__ void outk(const float* __restrict__ g, const float* __restrict__ Wo,
                     const float* __restrict__ bo, float* __restrict__ out){
    __shared__ float o1[B_*LABEL_];
    int t = threadIdx.x;
    if(t < B_*LABEL_){
        int b = t/LABEL_, j = t%LABEL_;
        float acc = bo[j];
        for(int k=0;k<H_;k++) acc += g[b*H_+k]*Wo[k*LABEL_+j];
        o1[t] = acc;
        out[t] = acc;
    }
    __syncthreads();
    if(t < LABEL_){
        float s = 0.f;
        for(int b=0;b<B_;b++) s += o1[b*LABEL_+t];
        out[B_*LABEL_+t] = s*(1.f/B_);
    }
}

// ---------------------------------------------------------------------------
extern "C" void kernel_launch(void* const* d_in, const int* in_sizes, int n_in,
                              void* d_out, int out_size, void* d_ws, size_t ws_size,
                              hipStream_t stream){
    const int*   node_text = (const int*)  d_in[2];
    const float* word_mask = (const float*)d_in[3];
    const float* E   = (const float*)d_in[7];
    const float* Wp  = (const float*)d_in[8];
    const float* bp  = (const float*)d_in[9];
    const float* Ws  = (const float*)d_in[10];
    const float* Us  = (const float*)d_in[11];
    const float* Vs  = (const float*)d_in[12];
    const float* bVs = (const float*)d_in[13];
    const float* WgW = (const float*)d_in[14];
    const float* Wgw = (const float*)d_in[15];
    const float* UgU = (const float*)d_in[16];
    const float* bgU = (const float*)d_in[17];
    const float* ugu = (const float*)d_in[18];
    const float* bgu = (const float*)d_in[19];
    const float* Wo  = (const float*)d_in[20];
    const float* bo  = (const float*)d_in[21];

    float* w = (float*)d_ws;
    size_t off = 0;
    auto alloc = [&](size_t nfloats){ float* p = w + off; off += nfloats; return p; };
    unsigned short* WaugT = (unsigned short*)alloc((size_t)NG_*KA_/2);   // 4 MB
    unsigned short* zpage = (unsigned short*)alloc(128);
    unsigned short* embbf = (unsigned short*)alloc((size_t)M_*EMB_/2);   // 8.4 MB
    unsigned short* hbf[2] = { (unsigned short*)alloc((size_t)M_*H_/2),
                               (unsigned short*)alloc((size_t)M_*H_/2) };
    float* cb[2]  = { alloc((size_t)M_*H_), alloc((size_t)M_*H_) };     // 16.8 MB each
    float* hu     = alloc((size_t)M_*H_);                                // 16.8 MB
    float* gpart  = alloc((size_t)B_*8*2*H_);
    float* gb[2]  = { alloc(B_*H_), alloc(B_*H_) };
    float* cgb[2] = { alloc(B_*H_), alloc(B_*H_) };
    float* havg   = alloc(B_*H_);
    float* smalls = alloc((size_t)B_*NS_);
    // total ~ 81 MB

    prep_waugT<<<(NG_*KA_)/256, 256, 0, stream>>>(Ws, Us, ugu, WaugT, zpage);
    emb_cast<<<M_, 256, 0, stream>>>(node_text, E, embbf);
    embed_gemm<<<dim3(H_/64, M_/64), 256, 0, stream>>>(node_text, E, Wp, bp,
                                                       word_mask, hbf[0], cb[0]);
    reduce_mean_s<<<B_, 1024, 0, stream>>>(hbf[0], gb[0], cgb[0]);

    int cur = 0;
    for(int layer=0; layer<3; layer++){
        int nxt = cur ^ 1;
        reduce_mean_s<<<B_, 1024, 0, stream>>>(hbf[cur], havg, nullptr);
        small_gemm<<<dim3(NS_/256, B_), 256, 0, stream>>>(gb[cur], havg, Vs, bVs,
                                                          Wgw, bgu, WgW, UgU, bgU, smalls);
        layer_mfma<<<dim3(NG_/BN, M_/BM), 256, 0, stream>>>(hbf[cur], embbf, WaugT, zpage,
                                                            cb[cur], cgb[cur], smalls, word_mask,
                                                            hbf[nxt], cb[nxt], hu);
        gcell1<<<B_*8, 256, 0, stream>>>(hu, cb[cur], word_mask, gpart);
        gcell2<<<B_, 256, 0, stream>>>(gpart, cgb[cur], smalls, gb[nxt], cgb[nxt]);
        cur = nxt;
    }
    outk<<<1, 512, 0, stream>>>(gb[cur], Wo, bo, (float*)d_out);
}

// Round 4
// 400.568 us; speedup vs baseline: 8.9540x; 1.1816x over previous
//
#include <hip/hip_runtime.h>
#include <math.h>

// Problem constants
#define B_      32
#define S_      512
#define H_      256
#define EMB_    256
#define M_      (B_*S_)     // 16384
#define N7_     1792        // 7*H
#define NG_     2048        // reordered gate width
#define NS_     2560        // smalls: 2048 reordered + 512 fo
#define KA_     1024        // augmented K: 3H (shifted h) + EMB (emb)
#define LABEL_  16

// GEMM tile
#define BM 128
#define BN 256
#define BK 32
#define EBM 64

typedef __bf16 bf16x8 __attribute__((ext_vector_type(8)));
typedef float  f32x4  __attribute__((ext_vector_type(4)));

__device__ __forceinline__ float sigf(float x){ return 1.f/(1.f+__expf(-x)); }

__device__ __forceinline__ unsigned short f2bf(float f){
    union { float f; unsigned int u; } v; v.f = f;
    unsigned int r = v.u + 0x7FFFu + ((v.u >> 16) & 1u);   // RNE
    return (unsigned short)(r >> 16);
}
__device__ __forceinline__ float bf2f(unsigned short u){
    union { unsigned int i; float f; } v; v.i = ((unsigned int)u) << 16; return v.f;
}

// ---------------------------------------------------------------------------
// WaugT[j=0..2047][k=0..1023] bf16, column order j = (t>>4)*128 + p*16 + (t&15):
//   p<7 : k<768 -> Ws[k][p*256+t] ; k>=768 -> Us[k-768][p*256+t]
//   p==7: k in [256,512) -> ugu[k-256][t], else 0    (f_w logits)
// Also zeroes the zero page (OOB staging target).
__global__ void prep_waugT(const float* __restrict__ Ws, const float* __restrict__ Us,
                           const float* __restrict__ ugu, unsigned short* __restrict__ WaugT,
                           unsigned short* __restrict__ zpage){
    if(blockIdx.x == 0) zpage[threadIdx.x] = 0;
    long idx = (long)blockIdx.x*256 + threadIdx.x;       // over 2048*1024
    int j = (int)(idx >> 10), k = (int)(idx & 1023);
    int tg = j >> 7, rem = j & 127, p = rem >> 4, t = tg*16 + (rem & 15);
    float v = 0.f;
    if(p < 7){
        int col = p*256 + t;
        v = (k < 768) ? Ws[(long)k*N7_ + col] : Us[(long)(k-768)*N7_ + col];
    } else if(k >= 256 && k < 512){
        v = ugu[(k-256)*H_ + t];
    }
    WaugT[idx] = f2bf(v);
}

// WpT[j][k] = bf16(Wp[k][j])
__global__ void prep_wpT(const float* __restrict__ Wp, unsigned short* __restrict__ WpT){
    int idx = blockIdx.x*256 + threadIdx.x;              // over 256*256
    int j = idx >> 8, k = idx & 255;
    WpT[idx] = f2bf(Wp[k*H_ + j]);
}

// embbf[i][k] = bf16(E[node_text[i]][k])
__global__ void emb_cast(const int* __restrict__ idx, const float* __restrict__ E,
                         unsigned short* __restrict__ embbf){
    int i = blockIdx.x, t = threadIdx.x;
    embbf[(size_t)i*EMB_ + t] = f2bf(E[(size_t)idx[i]*EMB_ + t]);
}

// ---------------------------------------------------------------------------
// Embed projection via MFMA: h0(bf16) = c0(f32) = (embbf @ WpT^T + bp) * mask
// M=16384, N=256, K=256; 2-phase double-buffered pipeline.
__global__ __launch_bounds__(256, 2) void embed_mfma(
        const unsigned short* __restrict__ embbf, const unsigned short* __restrict__ WpT,
        const float* __restrict__ bp, const float* __restrict__ mask,
        unsigned short* __restrict__ h0b, float* __restrict__ c0){
    __shared__ unsigned short As[2][EBM*BK];   //  4 KB x2
    __shared__ unsigned short Bs[2][H_*BK];    // 16 KB x2
    int tid = threadIdx.x, w = tid>>6, l = tid&63, fr = l&15, fq = l>>4;
    int m0 = blockIdx.x * EBM;
    f32x4 acc[4][4];
    #pragma unroll
    for(int m=0;m<4;m++)
        #pragma unroll
        for(int n=0;n<4;n++) acc[m][n] = (f32x4){0.f,0.f,0.f,0.f};

    auto stage = [&](int buf, int kt){
        {
            int row = tid >> 2;
            int k0 = ((tid & 3) ^ ((row >> 1) & 3)) * 8;
            const unsigned short* src = embbf + (size_t)(m0+row)*EMB_ + kt + k0;
            __builtin_amdgcn_global_load_lds(
                (const __attribute__((address_space(1))) unsigned int*)src,
                (__attribute__((address_space(3))) unsigned int*)(&As[buf][w*512]),
                16, 0, 0);
        }
        #pragma unroll
        for(int q=0;q<4;q++){
            int v = q*256 + tid;
            int col = v >> 2;
            int k0 = ((v & 3) ^ ((col >> 1) & 3)) * 8;
            const unsigned short* src = WpT + (size_t)col*EMB_ + kt + k0;
            __builtin_amdgcn_global_load_lds(
                (const __attribute__((address_space(1))) unsigned int*)src,
                (__attribute__((address_space(3))) unsigned int*)(&Bs[buf][(q*256 + w*64)*8]),
                16, 0, 0);
        }
    };

    stage(0, 0);
    __syncthreads();
    int cur = 0;
    for(int step=0; step<EMB_/BK; step++){
        if(step+1 < EMB_/BK) stage(cur^1, (step+1)*BK);
        bf16x8 bfv[4];
        #pragma unroll
        for(int n=0;n<4;n++){
            int colr = w*64 + n*16 + fr;
            int slot = fq ^ ((colr >> 1) & 3);
            bfv[n] = *(const bf16x8*)(&Bs[cur][colr*BK + slot*8]);
        }
        #pragma unroll
        for(int m=0;m<4;m++){
            int rowr = m*16 + fr;
            int slot = fq ^ ((rowr >> 1) & 3);
            bf16x8 af = *(const bf16x8*)(&As[cur][rowr*BK + slot*8]);
            #pragma unroll
            for(int n=0;n<4;n++)
                acc[m][n] = __builtin_amdgcn_mfma_f32_16x16x32_bf16(af, bfv[n], acc[m][n], 0,0,0);
        }
        __syncthreads();
        cur ^= 1;
    }
    #pragma unroll
    for(int m=0;m<4;m++){
        #pragma unroll
        for(int j=0;j<4;j++){
            int i = m0 + m*16 + fq*4 + j;
            float mk = mask[i];
            #pragma unroll
            for(int n=0;n<4;n++){
                int col = w*64 + n*16 + fr;
                float v = (acc[m][n][j] + bp[col]) * mk;
                h0b[(size_t)i*H_ + col] = f2bf(v);
                c0 [(size_t)i*H_ + col] = v;
            }
        }
    }
}

// ---------------------------------------------------------------------------
// mean over S of bf16 h (used once, for h0): outA/outB[b,h]
__global__ void reduce_mean_s(const unsigned short* __restrict__ h, float* __restrict__ outA,
                              float* __restrict__ outB){
    __shared__ float part[4][256];
    int b = blockIdx.x;
    int hh = threadIdx.x & 255, sg = threadIdx.x >> 8;
    float s = 0.f;
    long base = ((long)b*S_ + sg*128)*H_ + hh;
    for(int ss=0; ss<128; ss++) s += bf2f(h[base + (long)ss*H_]);
    part[sg][hh] = s;
    __syncthreads();
    if(threadIdx.x < 256){
        float t = (part[0][hh]+part[1][hh]+part[2][hh]+part[3][hh]) * (1.f/S_);
        outA[b*H_+hh] = t;
        if(outB) outB[b*H_+hh] = t;
    }
}

// ---------------------------------------------------------------------------
// smalls[32][2560]: cols 0:2048 reordered j=(t>>4)*128+p*16+(t&15):
//   p<7 -> bVs[p*256+t] + g@Vs[:,p*256+t] ;  p==7 -> bgu[t] + g@Wgw[:,t]
// cols 2048:2560 = sigmoid(g@WgW + h_avg@UgU + bgU)  (f_g | o_g)
__global__ void small_gemm(const float* __restrict__ g, const float* __restrict__ havg,
                           const float* __restrict__ Vs, const float* __restrict__ bVs,
                           const float* __restrict__ Wgw, const float* __restrict__ bgu,
                           const float* __restrict__ WgW, const float* __restrict__ UgU,
                           const float* __restrict__ bgU, float* __restrict__ smalls){
    __shared__ float gs[256], hs[256];
    int b = blockIdx.y, t0 = threadIdx.x;
    gs[t0] = g[b*H_+t0];
    hs[t0] = havg[b*H_+t0];
    __syncthreads();
    int j = blockIdx.x*256 + t0;
    float acc;
    if(j < NG_){
        int tg = j >> 7, rem = j & 127, p = rem >> 4, t = tg*16 + (rem & 15);
        if(p < 7){
            int col = p*256 + t;
            acc = bVs[col];
            for(int k=0;k<H_;k++) acc += gs[k]*Vs[k*N7_+col];
        } else {
            acc = bgu[t];
            for(int k=0;k<H_;k++) acc += gs[k]*Wgw[k*H_+t];
        }
    } else {
        int jj = j - NG_;
        acc = bgU[jj];
        for(int k=0;k<H_;k++) acc += gs[k]*WgW[k*512+jj] + hs[k]*UgU[k*512+jj];
        acc = sigf(acc);
    }
    smalls[b*NS_+j] = acc;
}

// ---------------------------------------------------------------------------
// MFMA gates-GEMM (M=16384, N=2048, K=1024), 2-phase double-buffered, fused
// SCell epilogue + in-register GCell softmax partials + h-mean partials.
__global__ __launch_bounds__(256, 2) void layer_mfma(
        const unsigned short* __restrict__ hbf, const unsigned short* __restrict__ embbf,
        const unsigned short* __restrict__ WaugT, const unsigned short* __restrict__ zpage,
        const float* __restrict__ c_old, const float* __restrict__ cg_old,
        const float* __restrict__ smalls, const float* __restrict__ mask,
        unsigned short* __restrict__ hbf_new, float* __restrict__ c_new,
        float* __restrict__ lpart, float* __restrict__ apart, float* __restrict__ hpart){
    __shared__ unsigned short As[2][BM*BK];   //  8 KB x2
    __shared__ unsigned short Bs[2][BN*BK];   // 16 KB x2
    __shared__ float red[4][16][3];
    int tid = threadIdx.x;
    int w = tid >> 6, l = tid & 63;
    int fr = l & 15, fq = l >> 4;
    int wr = w >> 1, wc = w & 1;
    int n0 = blockIdx.x * BN;
    int m0 = blockIdx.y * BM;
    int b  = m0 >> 9;

    f32x4 acc[4][8];
    #pragma unroll
    for(int m=0;m<4;m++)
        #pragma unroll
        for(int n=0;n<8;n++) acc[m][n] = (f32x4){0.f,0.f,0.f,0.f};

    auto stage = [&](int buf, int kt){
        int region = kt >> 8;
        #pragma unroll
        for(int q=0;q<2;q++){
            int u = q*256 + tid;
            int row = u >> 2;
            int k0 = ((u & 3) ^ ((row >> 1) & 3)) * 8;
            const unsigned short* src;
            if(region < 3){
                int i  = m0 + row;
                int si = (i & (S_-1)) + region - 1;
                src = ((unsigned)si < (unsigned)S_)
                    ? hbf + (size_t)(i + region - 1)*H_ + (kt & 255) + k0
                    : zpage + k0;
            } else {
                src = embbf + (size_t)(m0 + row)*EMB_ + (kt - 768) + k0;
            }
            __builtin_amdgcn_global_load_lds(
                (const __attribute__((address_space(1))) unsigned int*)src,
                (__attribute__((address_space(3))) unsigned int*)(&As[buf][(q*256 + w*64)*8]),
                16, 0, 0);
        }
        #pragma unroll
        for(int q=0;q<4;q++){
            int v = q*256 + tid;
            int col = v >> 2;
            int k0 = ((v & 3) ^ ((col >> 1) & 3)) * 8;
            const unsigned short* src = WaugT + (size_t)(n0 + col)*KA_ + kt + k0;
            __builtin_amdgcn_global_load_lds(
                (const __attribute__((address_space(1))) unsigned int*)src,
                (__attribute__((address_space(3))) unsigned int*)(&Bs[buf][(q*256 + w*64)*8]),
                16, 0, 0);
        }
    };

    stage(0, 0);
    __syncthreads();
    int cur = 0;
    for(int step=0; step<KA_/BK; step++){
        if(step+1 < KA_/BK) stage(cur^1, (step+1)*BK);
        bf16x8 bfv[8];
        #pragma unroll
        for(int n=0;n<8;n++){
            int colr = wc*128 + n*16 + fr;
            int slot = fq ^ ((colr >> 1) & 3);
            bfv[n] = *(const bf16x8*)(&Bs[cur][colr*BK + slot*8]);
        }
        #pragma unroll
        for(int m=0;m<4;m++){
            int rowr = wr*64 + m*16 + fr;
            int slot = fq ^ ((rowr >> 1) & 3);
            bf16x8 af = *(const bf16x8*)(&As[cur][rowr*BK + slot*8]);
            #pragma unroll
            for(int n=0;n<8;n++)
                acc[m][n] = __builtin_amdgcn_mfma_f32_16x16x32_bf16(af, bfv[n], acc[m][n], 0,0,0);
        }
        __syncthreads();
        cur ^= 1;
    }

    // ---- fused SCell epilogue + GCell/h-mean partial reductions
    int t = (n0 >> 3) + wc*16 + fr;
    float sm[8];
    #pragma unroll
    for(int n=0;n<8;n++) sm[n] = smalls[b*NS_ + n0 + wc*128 + n*16 + fr];
    float cgv = cg_old[b*H_ + t];
    float lsum = 0.f, asum = 0.f, hsum = 0.f;
    #pragma unroll
    for(int m=0;m<4;m++){
        #pragma unroll
        for(int j=0;j<4;j++){
            int i = m0 + wr*64 + m*16 + fq*4 + j;
            int s = i & (S_-1);
            float gv[8];
            #pragma unroll
            for(int n=0;n<8;n++) gv[n] = acc[m][n][j] + sm[n];
            float ei=__expf(sigf(gv[0])), el=__expf(sigf(gv[1])), er=__expf(sigf(gv[2]));
            float ef=__expf(sigf(gv[3])), es=__expf(sigf(gv[4]));
            float inv = 1.f/(ei+el+er+ef+es);
            float c0v = c_old[(size_t)i*H_ + t];
            float cbv = (s>0)      ? c_old[(size_t)(i-1)*H_ + t] : 0.f;
            float cav = (s<S_-1)   ? c_old[(size_t)(i+1)*H_ + t] : 0.f;
            float tu = tanhf(gv[6]);
            float nc = (cbv*el + c0v*ef + er*cav + es*cgv + ei*tu)*inv;
            float nh = gv[5]*tanhf(nc);
            float mk = mask[i];
            float ncm = nc*mk, nhm = nh*mk;
            c_new [(size_t)i*H_ + t] = ncm;
            hbf_new[(size_t)i*H_ + t] = f2bf(nhm);
            float e = __expf(sigf(gv[7]) - (1.f - mk)*1e16f);
            lsum += e;
            asum += e*c0v;
            hsum += nhm;
        }
    }
    // reduce over fq (rows) within wave
    #pragma unroll
    for(int off=16; off<64; off<<=1){
        lsum += __shfl_xor(lsum, off);
        asum += __shfl_xor(asum, off);
        hsum += __shfl_xor(hsum, off);
    }
    if(l < 16){ red[w][l][0]=lsum; red[w][l][1]=asum; red[w][l][2]=hsum; }
    __syncthreads();
    if(tid < 32){
        int wc2 = tid >> 4, fr2 = tid & 15;
        float L  = red[wc2][fr2][0] + red[2+wc2][fr2][0];
        float A  = red[wc2][fr2][1] + red[2+wc2][fr2][1];
        float Hh = red[wc2][fr2][2] + red[2+wc2][fr2][2];
        int tt = (n0 >> 3) + wc2*16 + fr2;
        int by = blockIdx.y;
        lpart[by*H_ + tt] = L;
        apart[by*H_ + tt] = A;
        hpart[by*H_ + tt] = Hh;
    }
}

// ---------------------------------------------------------------------------
// Combine per-row-chunk partials: g_new, cg_new, havg (mean of h_new over S).
__global__ void gcell2x(const float* __restrict__ lpart, const float* __restrict__ apart,
                        const float* __restrict__ hpart, const float* __restrict__ cg_old,
                        const float* __restrict__ smalls,
                        float* __restrict__ g_new, float* __restrict__ cg_new,
                        float* __restrict__ havg_out){
    int b = blockIdx.x, t = threadIdx.x;
    float L = 0.f, A = 0.f, Hs = 0.f;
    for(int ci=0; ci<4; ci++){
        int by = b*4 + ci;
        L  += lpart[by*H_ + t];
        A  += apart[by*H_ + t];
        Hs += hpart[by*H_ + t];
    }
    float fg = smalls[b*NS_ + NG_ + t];
    float og = smalls[b*NS_ + NG_ + 256 + t];
    float ncg = fg*cg_old[b*H_+t] + A/L;
    g_new[b*H_+t]    = og*tanhf(ncg);
    cg_new[b*H_+t]   = ncg;
    havg_out[b*H_+t] = Hs * (1.f/S_);
}

// ---------------------------------------------------------------------------
// out[0:512] = g@Wo + bo ; out[512:528] = mean over b of the first part
__global__ void outk(const float* __restrict__ g, const float* __restrict__ Wo,
                     const float* __restrict__ bo, float* __restrict__ out){
    __shared__ float o1[B_*LABEL_];
    int t = threadIdx.x;
    if(t < B_*LABEL_){
        int b = t/LABEL_, j = t%LABEL_;
        float acc = bo[j];
        for(int k=0;k<H_;k++) acc += g[b*H_+k]*Wo[k*LABEL_+j];
        o1[t] = acc;
        out[t] = acc;
    }
    __syncthreads();
    if(t < LABEL_){
        float s = 0.f;
        for(int b=0;b<B_;b++) s += o1[b*LABEL_+t];
        out[B_*LABEL_+t] = s*(1.f/B_);
    }
}

// ---------------------------------------------------------------------------
extern "C" void kernel_launch(void* const* d_in, const int* in_sizes, int n_in,
                              void* d_out, int out_size, void* d_ws, size_t ws_size,
                              hipStream_t stream){
    const int*   node_text = (const int*)  d_in[2];
    const float* word_mask = (const float*)d_in[3];
    const float* E   = (const float*)d_in[7];
    const float* Wp  = (const float*)d_in[8];
    const float* bp  = (const float*)d_in[9];
    const float* Ws  = (const float*)d_in[10];
    const float* Us  = (const float*)d_in[11];
    const float* Vs  = (const float*)d_in[12];
    const float* bVs = (const float*)d_in[13];
    const float* WgW = (const float*)d_in[14];
    const float* Wgw = (const float*)d_in[15];
    const float* UgU = (const float*)d_in[16];
    const float* bgU = (const float*)d_in[17];
    const float* ugu = (const float*)d_in[18];
    const float* bgu = (const float*)d_in[19];
    const float* Wo  = (const float*)d_in[20];
    const float* bo  = (const float*)d_in[21];

    float* w = (float*)d_ws;
    size_t off = 0;
    auto alloc = [&](size_t nfloats){ float* p = w + off; off += nfloats; return p; };
    unsigned short* WaugT = (unsigned short*)alloc((size_t)NG_*KA_/2);   // 4 MB
    unsigned short* zpage = (unsigned short*)alloc(128);
    unsigned short* WpT   = (unsigned short*)alloc((size_t)H_*EMB_/2);   // 128 KB
    unsigned short* embbf = (unsigned short*)alloc((size_t)M_*EMB_/2);   // 8.4 MB
    unsigned short* hbf[2] = { (unsigned short*)alloc((size_t)M_*H_/2),
                               (unsigned short*)alloc((size_t)M_*H_/2) };
    float* cb[2]  = { alloc((size_t)M_*H_), alloc((size_t)M_*H_) };     // 16.8 MB each
    float* lpart  = alloc((size_t)(M_/BM)*H_);
    float* apart  = alloc((size_t)(M_/BM)*H_);
    float* hpart  = alloc((size_t)(M_/BM)*H_);
    float* gb[2]  = { alloc(B_*H_), alloc(B_*H_) };
    float* cgb[2] = { alloc(B_*H_), alloc(B_*H_) };
    float* havg   = alloc(B_*H_);
    float* smalls = alloc((size_t)B_*NS_);
    // total ~ 62 MB

    prep_waugT<<<(NG_*KA_)/256, 256, 0, stream>>>(Ws, Us, ugu, WaugT, zpage);
    prep_wpT<<<(H_*EMB_)/256, 256, 0, stream>>>(Wp, WpT);
    emb_cast<<<M_, 256, 0, stream>>>(node_text, E, embbf);
    embed_mfma<<<M_/EBM, 256, 0, stream>>>(embbf, WpT, bp, word_mask, hbf[0], cb[0]);
    reduce_mean_s<<<B_, 1024, 0, stream>>>(hbf[0], gb[0], cgb[0]);

    int cur = 0;
    for(int layer=0; layer<3; layer++){
        int nxt = cur ^ 1;
        const float* havg_in = (layer == 0) ? gb[0] : havg;
        small_gemm<<<dim3(NS_/256, B_), 256, 0, stream>>>(gb[cur], havg_in, Vs, bVs,
                                                          Wgw, bgu, WgW, UgU, bgU, smalls);
        layer_mfma<<<dim3(NG_/BN, M_/BM), 256, 0, stream>>>(hbf[cur], embbf, WaugT, zpage,
                                                            cb[cur], cgb[cur], smalls, word_mask,
                                                            hbf[nxt], cb[nxt],
                                                            lpart, apart, hpart);
        gcell2x<<<B_, 256, 0, stream>>>(lpart, apart, hpart, cgb[cur], smalls,
                                        gb[nxt], cgb[nxt], havg);
        cur = nxt;
    }
    outk<<<1, 512, 0, stream>>>(gb[cur], Wo, bo, (float*)d_out);
}